// Round 1
// 425.727 us; speedup vs baseline: 1.0422x; 1.0422x over previous
//
#include <hip/hip_runtime.h>

typedef unsigned short u16;
typedef __attribute__((ext_vector_type(8))) short short8;
typedef __attribute__((ext_vector_type(4))) float floatx4;

#define MFMA16(A, B, C) __builtin_amdgcn_mfma_f32_16x16x32_bf16((A), (B), (C), 0, 0, 0)

// ws layout (u16 element offsets)
#define OF_SPEC  64                       // canonical bf16 spec [204800]
#define OF_SMALL (OF_SPEC + 204800)       // W1(0) b1(256) fq(512) fk(768) fv(1024) fb(1280)
#define OF_PART  (OF_SMALL + 1536)        // 8x256 f32 partials for fused bp (4096 u16)
#define OF_FW    (OF_PART + 4096)         // fused weights frag-major: Wq' Wk' Wv' (3x65536) + Wp'(524288)

static __device__ __forceinline__ float bf2f(u16 u) {
  union { unsigned int i; float f; } z; z.i = ((unsigned int)u) << 16; return z.f;
}
static __device__ __forceinline__ u16 f2bf(float f) {
  union { float f; unsigned int i; } z; z.f = f;
  unsigned int x = z.i + 0x7fffu + ((z.i >> 16) & 1u);  // RNE
  return (u16)(x >> 16);
}
static __device__ __forceinline__ void ld8f(const u16* p, float* o) {
  union { short8 v; u16 u[8]; } t;
  t.v = *(const short8*)p;
#pragma unroll
  for (int j = 0; j < 8; ++j) o[j] = bf2f(t.u[j]);
}

// bf16 (flag=0) vs f32 (flag=1) input detection on first 256 u16 of spec.
__global__ void detect_kernel(const u16* __restrict__ spec_u16, int* __restrict__ flag) {
  const int lane = threadIdx.x;
  int bad = 0;
#pragma unroll
  for (int j = 0; j < 4; ++j) {
    u16 v = spec_u16[lane * 4 + j];
    int e = (v >> 7) & 0xFF;
    bad += (e >= 137);
  }
  unsigned long long m = __ballot(bad > 0);
  if (lane == 0) *flag = (__popcll(m) >= 4) ? 1 : 0;
}

#define CV(src, idx) (flag ? f2bf(((const float*)(src))[idx]) : ((const u16*)(src))[idx])

// Canonicalize spec + W1/b1 to bf16. Weight swizzling now happens inside fold_kernel.
__global__ void prep_kernel(const int* __restrict__ flagp,
                            const void* spec, const void* W1, const void* b1,
                            u16* __restrict__ ws) {
  const int flag = *flagp;
  int i = blockIdx.x * 256 + threadIdx.x;
  if (i < 204800) { ws[OF_SPEC + i] = CV(spec, i); return; }
  int j = i - 204800;
  if (j < 256) ws[OF_SMALL + j] = CV(W1, j);
  else         ws[OF_SMALL + j] = CV(b1, j - 256);
}

// Weight folding. Blocks 0..175: 11 GEMMs of 256x256x256 (16 sub-blocks of 64x64 each):
//   g=0..2:  Wg' = W2 @ {Wq,Wk,Wv}      (q = relu(s*W1+b1) @ Wg' + fg)
//   g=3..10: Wp'_p = Wo @ Wp[p*256:...]  (patch = sum_p o_raw_p @ Wp'_p + fb)
// Output written bf16 fragment-major: dst[(k>>3)*2048 + n*8 + (k&7)].
// Blocks 176..186: fused bias vectors fq/fk/fv and the 8 partials for fb.
__global__ void fold_kernel(const int* __restrict__ flagp,
    const void* W2, const void* Wq, const void* Wk, const void* Wv,
    const void* Wo, const void* Wp,
    const void* b2, const void* bq, const void* bk, const void* bvv, const void* bo,
    u16* __restrict__ ws) {
  const int flag = *flagp;
  const int f = blockIdx.x;
  if (f >= 176) {
    const int t = f - 176;
    const int n = threadIdx.x;
    if (t < 3) {
      const void* SB = (t == 0) ? Wq : (t == 1) ? Wk : Wv;
      const void* bs = (t == 0) ? bq : (t == 1) ? bk : bvv;
      float acc = bf2f(CV(bs, n));
      for (int k = 0; k < 256; ++k)
        acc = fmaf(bf2f(CV(b2, k)), bf2f(CV(SB, k * 256 + n)), acc);
      ws[OF_SMALL + 512 + t * 256 + n] = f2bf(acc);
    } else {
      const int p = t - 3;
      float acc = 0.f;
      for (int m = 0; m < 256; ++m)
        acc = fmaf(bf2f(CV(bo, m)), bf2f(CV(Wp, (p * 256 + m) * 256 + n)), acc);
      ((float*)(ws + OF_PART))[p * 256 + n] = acc;
    }
    return;
  }
  const int g = f >> 4, sub = f & 15;
  const int r0 = (sub >> 2) * 64, c0 = (sub & 3) * 64;
  const void* SA = (g < 3) ? W2 : Wo;
  const void* SB = (g == 0) ? Wq : (g == 1) ? Wk : (g == 2) ? Wv : Wp;
  const int brow0 = (g < 3) ? 0 : (g - 3) * 256;   // also the output-k offset for Wp'
  const int tid = threadIdx.x;
  const int w = tid >> 6, lane = tid & 63, l15 = lane & 15, quad = lane >> 4;
  const int arow = r0 + w * 16 + l15;
  floatx4 acc[4];
#pragma unroll
  for (int ni = 0; ni < 4; ++ni) acc[ni] = (floatx4){0.f, 0.f, 0.f, 0.f};
  for (int kc = 0; kc < 8; ++kc) {
    const int k0 = kc * 32 + quad * 8;
    union { short8 s8; u16 u[8]; } av;
#pragma unroll
    for (int j = 0; j < 8; ++j) av.u[j] = CV(SA, arow * 256 + k0 + j);
#pragma unroll
    for (int ni = 0; ni < 4; ++ni) {
      const int colx = c0 + ni * 16 + l15;
      union { short8 s8; u16 u[8]; } bu;
#pragma unroll
      for (int j = 0; j < 8; ++j) bu.u[j] = CV(SB, (brow0 + k0 + j) * 256 + colx);
      acc[ni] = MFMA16(av.s8, bu.s8, acc[ni]);
    }
  }
  u16* dst = ws + OF_FW + ((g < 3) ? g * 65536 : 3 * 65536);
#pragma unroll
  for (int ni = 0; ni < 4; ++ni) {
    const int n = c0 + ni * 16 + l15;
#pragma unroll
    for (int r = 0; r < 4; ++r) {
      const int k = brow0 + r0 + w * 16 + quad * 4 + r;
      dst[(k >> 3) * 2048 + n * 8 + (k & 7)] = f2bf(acc[ni][r]);
    }
  }
}

__global__ void bfin_kernel(const int* __restrict__ flagp, const void* bp,
                            u16* __restrict__ ws) {
  const int flag = *flagp;
  const int n = threadIdx.x;
  const float* part = (const float*)(ws + OF_PART);
  float s = bf2f(CV(bp, n));
#pragma unroll
  for (int p = 0; p < 8; ++p) s += part[p * 256 + n];
  ws[OF_SMALL + 1280 + n] = f2bf(s);
}

// One block = 64 tokens = 8 windows, fully fused. W2 folded into Wq/Wk/Wv
// (so the A operand is just relu(s*W1+b1)); Wo folded into Wp (attention
// output goes straight to the patch GEMM via registers).
__global__ __launch_bounds__(256, 2) void fused_kernel(
    const u16* __restrict__ csp, const u16* __restrict__ csm,
    const u16* __restrict__ sWq, const u16* __restrict__ sWk,
    const u16* __restrict__ sWv, const u16* __restrict__ sWp,
    const int* __restrict__ flagp,
    void* __restrict__ out)
{
  __shared__ u16 lds[28672];          // 57344 B -> 2 blocks/CU
  u16* aA = lds;                      // 16384: frag-major a[m<64][k<256]; later patchA
  u16* qb = lds + 16384;              // 64 x 64, XOR-swizzled cols
  u16* kb = qb + 4096;
  u16* vb = kb + 4096;

  const u16* cW1 = csm;
  const u16* cb1 = csm + 256;
  const u16* cfq = csm + 512;
  const u16* cfk = csm + 768;
  const u16* cfv = csm + 1024;
  const u16* cfb = csm + 1280;

  const int flag = *flagp;
  const int tid = threadIdx.x;
  const int wave = tid >> 6, lane = tid & 63;
  const int l15 = lane & 15, quad = lane >> 4;
  const int tile0 = blockIdx.x * 64;

  // ---------------- a-fill: relu(s*W1+b1) -> aA fragment-major ----------------
  {
    const int m = tid & 63;
    const int k8base = (tid >> 6) * 8;
    const float s = bf2f(csp[tile0 + m]);
#pragma unroll
    for (int c = 0; c < 8; ++c) {
      const int k8 = k8base + c;
      float w1f[8], b1f[8];
      ld8f(cW1 + k8 * 8, w1f);
      ld8f(cb1 + k8 * 8, b1f);
      union { short8 s8; u16 u[8]; } t;
#pragma unroll
      for (int j = 0; j < 8; ++j) {
        float x = fmaf(s, w1f[j], b1f[j]);
        t.u[j] = f2bf(x > 0.f ? x : 0.f);
      }
      *(short8*)(aA + k8 * 512 + m * 8) = t.s8;
    }
  }
  __syncthreads();

  short8 obf[8];                      // attention outputs, 2 x short8 per chunk

  // ---------------- 4 chunks of 2 heads (64 cols) each ------------------
#pragma unroll
  for (int c = 0; c < 4; ++c) {
    const int nb_c = c * 64;
    const int col = nb_c + wave * 16 + l15;

    // q,k,v GEMMs (fused weights: K=256 over a)
    {
      floatx4 facc[3][4];
#pragma unroll
      for (int x = 0; x < 3; ++x)
#pragma unroll
        for (int mi = 0; mi < 4; ++mi) facc[x][mi] = (floatx4){0.f, 0.f, 0.f, 0.f};
      for (int kc = 0; kc < 8; ++kc) {
        short8 afr[4];
#pragma unroll
        for (int mi = 0; mi < 4; ++mi)
          afr[mi] = *(const short8*)(aA + (kc * 4 + quad) * 512 + (mi * 16 + l15) * 8);
        const int wo = ((kc * 4 + quad) * 256 + col) * 8;
        short8 bq8 = *(const short8*)(sWq + wo);
        short8 bk8 = *(const short8*)(sWk + wo);
        short8 bv8 = *(const short8*)(sWv + wo);
#pragma unroll
        for (int mi = 0; mi < 4; ++mi) {
          facc[0][mi] = MFMA16(afr[mi], bq8, facc[0][mi]);
          facc[1][mi] = MFMA16(afr[mi], bk8, facc[1][mi]);
          facc[2][mi] = MFMA16(afr[mi], bv8, facc[2][mi]);
        }
      }
      const int lc = wave * 16 + l15;
      const float bqv = bf2f(cfq[col]), bkv = bf2f(cfk[col]), bvv = bf2f(cfv[col]);
#pragma unroll
      for (int mi = 0; mi < 4; ++mi)
#pragma unroll
        for (int r = 0; r < 4; ++r) {
          const int tr = mi * 16 + quad * 4 + r;
          const int rr = tr * 64 + ((((lc >> 3) ^ (tr & 7)) << 3) | (lc & 7));
          qb[rr] = f2bf(facc[0][mi][r] + bqv);
          kb[rr] = f2bf(facc[1][mi][r] + bkv);
          vb[rr] = f2bf(facc[2][mi][r] + bvv);
        }
    }
    __syncthreads();

    // attention: 16 window-heads x (8 rows x 2 halves); halves split the
    // 32-dim dot and combine with one shfl_xor. Output kept in registers.
    {
      const int wh = tid >> 4, win = wh >> 1, hl = wh & 1;
      const int sub = tid & 15, row = sub >> 1, half = sub & 1;
      const int cb0 = hl * 4 + half * 2;   // col8 base of this thread's 16 dims
      const u16* qbase = qb + (win * 8 + row) * 64;
      float qf[16];
      ld8f(qbase + ((cb0 ^ row) << 3), qf);
      ld8f(qbase + (((cb0 + 1) ^ row) << 3), qf + 8);
      float s[8];
#pragma unroll
      for (int kk = 0; kk < 8; ++kk) {
        const u16* kbase = kb + (win * 8 + kk) * 64;
        float kf[8], a = 0.f;
        ld8f(kbase + ((cb0 ^ kk) << 3), kf);
#pragma unroll
        for (int j = 0; j < 8; ++j) a = fmaf(qf[j], kf[j], a);
        ld8f(kbase + (((cb0 + 1) ^ kk) << 3), kf);
#pragma unroll
        for (int j = 0; j < 8; ++j) a = fmaf(qf[8 + j], kf[j], a);
        a += __shfl_xor(a, 1);
        s[kk] = a * 0.17677669529663687f;  // 1/sqrt(32)
      }
      float mx = s[0];
#pragma unroll
      for (int kk = 1; kk < 8; ++kk) mx = fmaxf(mx, s[kk]);
      float p[8], sum = 0.f;
#pragma unroll
      for (int kk = 0; kk < 8; ++kk) { p[kk] = __expf(s[kk] - mx); sum += p[kk]; }
      const float inv = 1.f / sum;
      float o[16];
#pragma unroll
      for (int d = 0; d < 16; ++d) o[d] = 0.f;
#pragma unroll
      for (int kk = 0; kk < 8; ++kk) {
        const u16* vbase = vb + (win * 8 + kk) * 64;
        float vf[16];
        ld8f(vbase + ((cb0 ^ kk) << 3), vf);
        ld8f(vbase + (((cb0 + 1) ^ kk) << 3), vf + 8);
        const float pk = p[kk] * inv;
#pragma unroll
        for (int d = 0; d < 16; ++d) o[d] = fmaf(pk, vf[d], o[d]);
      }
      union { short8 s8; u16 u[8]; } t0, t1;
#pragma unroll
      for (int j = 0; j < 8; ++j) { t0.u[j] = f2bf(o[j]); t1.u[j] = f2bf(o[8 + j]); }
      obf[c * 2] = t0.s8;
      obf[c * 2 + 1] = t1.s8;
    }
    if (c < 3) __syncthreads();
  }

  // write all attention outputs to patchA (reusing aA region), frag-major over
  // k in [0,2048): k = p*256 + d, addr = (p*32 + (d>>3))*64 + win*8 + (d&7)
  {
    const int wh = tid >> 4, win = wh >> 1, hl = wh & 1;
    const int sub = tid & 15, row = sub >> 1, half = sub & 1;
    const int cb0 = hl * 4 + half * 2;
#pragma unroll
    for (int c = 0; c < 4; ++c) {
      const int g = c * 8 + cb0;
      *(short8*)(aA + (row * 32 + g) * 64 + win * 8) = obf[c * 2];
      *(short8*)(aA + (row * 32 + g + 1) * 64 + win * 8) = obf[c * 2 + 1];
    }
  }
  __syncthreads();

  // ---------------- patch projection: [8 x 2048] @ Wp' + fb ----------------
  // A-frag lanes 8..15 broadcast rows 0..7 (same address, free); their output
  // rows are discarded.
  {
    const int w8 = (l15 & 7) * 8;
    floatx4 pacc[4];
#pragma unroll
    for (int ni = 0; ni < 4; ++ni) pacc[ni] = (floatx4){0.f, 0.f, 0.f, 0.f};
#pragma unroll 4
    for (int kc = 0; kc < 64; ++kc) {
      short8 afr = *(const short8*)(aA + (kc * 4 + quad) * 64 + w8);
#pragma unroll
      for (int ni = 0; ni < 4; ++ni) {
        const int n = wave * 64 + ni * 16 + l15;
        short8 bfr = *(const short8*)(sWp + ((kc * 4 + quad) * 256 + n) * 8);
        pacc[ni] = MFMA16(afr, bfr, pacc[ni]);
      }
    }
    if (quad < 2) {
      if (flag) {
        float* po = (float*)out;
#pragma unroll
        for (int ni = 0; ni < 4; ++ni) {
          const int n = wave * 64 + ni * 16 + l15;
          const float bb = bf2f(cfb[n]);
#pragma unroll
          for (int r = 0; r < 4; ++r)
            po[(blockIdx.x * 8 + quad * 4 + r) * 256 + n] = pacc[ni][r] + bb;
        }
      } else {
        u16* po = (u16*)out;
#pragma unroll
        for (int ni = 0; ni < 4; ++ni) {
          const int n = wave * 64 + ni * 16 + l15;
          const float bb = bf2f(cfb[n]);
#pragma unroll
          for (int r = 0; r < 4; ++r)
            po[(blockIdx.x * 8 + quad * 4 + r) * 256 + n] = f2bf(pacc[ni][r] + bb);
        }
      }
    }
  }
}

extern "C" void kernel_launch(void* const* d_in, const int* in_sizes, int n_in,
                              void* d_out, int out_size, void* d_ws, size_t ws_size,
                              hipStream_t stream) {
  (void)in_sizes; (void)n_in; (void)out_size; (void)ws_size;
  int* flag = (int*)d_ws;
  u16* ws = (u16*)d_ws;

  detect_kernel<<<1, 64, 0, stream>>>((const u16*)d_in[0], flag);
  prep_kernel<<<802, 256, 0, stream>>>(flag, d_in[0], d_in[1], d_in[2], ws);
  fold_kernel<<<187, 256, 0, stream>>>(flag,
      d_in[3], d_in[5], d_in[7], d_in[9], d_in[11], d_in[13],
      d_in[4], d_in[6], d_in[8], d_in[10], d_in[12], ws);
  bfin_kernel<<<1, 256, 0, stream>>>(flag, d_in[14], ws);
  fused_kernel<<<3200, 256, 0, stream>>>(
      ws + OF_SPEC, ws + OF_SMALL,
      ws + OF_FW, ws + OF_FW + 65536, ws + OF_FW + 2 * 65536, ws + OF_FW + 3 * 65536,
      flag, d_out);
}